// Round 1
// baseline (434.817 us; speedup 1.0000x reference)
//
#include <hip/hip_runtime.h>
#include <hip/hip_bf16.h>
#include <cstdint>
#include <cstddef>

typedef __bf16 bf16;
typedef __bf16 bf16x4 __attribute__((ext_vector_type(4)));
typedef __bf16 bf16x8 __attribute__((ext_vector_type(8)));
typedef float  f32x4  __attribute__((ext_vector_type(4)));

#define MB   8192
#define NN   4096
#define RR   16
#define KOUT 4096

// ---------------------------------------------------------------------------
// async global->LDS (16B per lane). LDS dest: wave-uniform base + lane*16.
__device__ __forceinline__ void gload_lds16(const bf16* g, bf16* l) {
  __builtin_amdgcn_global_load_lds(
      (const __attribute__((address_space(1))) void*)g,
      (__attribute__((address_space(3))) void*)l, 16, 0, 0);
}

// ---------------------------------------------------------------------------
// Kernel 1: per block = 16 rows of x.
//   Phase A: S[16][16] = x_rows @ H^T  (f32, register-blocked, shuffle-reduce)
//   Phase B: h = relu(S @ G + b1) -> bf16 out
__global__ __launch_bounds__(256) void k1_lowrank(
    const float* __restrict__ x, const float* __restrict__ G,
    const float* __restrict__ H, const float* __restrict__ b1,
    bf16* __restrict__ hout)
{
  __shared__ float sS[16][16];
  const int t    = threadIdx.x;
  const int lane = t & 63;
  const int wave = t >> 6;
  const int r0   = blockIdx.x * 16;
  const int i0   = wave * 4;          // each wave owns 4 rows

  float acc[4][RR];
#pragma unroll
  for (int j = 0; j < 4; ++j)
#pragma unroll
    for (int r = 0; r < RR; ++r) acc[j][r] = 0.f;

  for (int kt = 0; kt < NN; kt += 256) {
    const int k = kt + lane * 4;
    f32x4 xv[4];
#pragma unroll
    for (int j = 0; j < 4; ++j)
      xv[j] = *(const f32x4*)(x + (size_t)(r0 + i0 + j) * NN + k);
#pragma unroll
    for (int r = 0; r < RR; ++r) {
      const f32x4 hv = *(const f32x4*)(H + (size_t)r * NN + k);
#pragma unroll
      for (int j = 0; j < 4; ++j) {
        acc[j][r] = fmaf(xv[j].x, hv.x, acc[j][r]);
        acc[j][r] = fmaf(xv[j].y, hv.y, acc[j][r]);
        acc[j][r] = fmaf(xv[j].z, hv.z, acc[j][r]);
        acc[j][r] = fmaf(xv[j].w, hv.w, acc[j][r]);
      }
    }
  }

  // reduce each of the 64 partials across the 64 lanes
#pragma unroll
  for (int j = 0; j < 4; ++j)
#pragma unroll
    for (int r = 0; r < RR; ++r) {
      float v = acc[j][r];
#pragma unroll
      for (int off = 32; off >= 1; off >>= 1) v += __shfl_xor(v, off, 64);
      acc[j][r] = v;
    }
  if (lane == 0) {
#pragma unroll
    for (int j = 0; j < 4; ++j)
#pragma unroll
      for (int r = 0; r < RR; ++r) sS[i0 + j][r] = acc[j][r];
  }
  __syncthreads();

  // Phase B: each thread owns 4 contiguous cols per 1024-col chunk
#pragma unroll
  for (int chunk = 0; chunk < 4; ++chunk) {
    const int c = chunk * 1024 + t * 4;
    const f32x4 b1v = *(const f32x4*)(b1 + c);
#pragma unroll
    for (int ib = 0; ib < 16; ib += 4) {
      f32x4 a0 = {0.f,0.f,0.f,0.f}, a1 = a0, a2 = a0, a3 = a0;
#pragma unroll
      for (int rb = 0; rb < 16; rb += 4) {
        const f32x4 sv0 = *(const f32x4*)&sS[ib + 0][rb];
        const f32x4 sv1 = *(const f32x4*)&sS[ib + 1][rb];
        const f32x4 sv2 = *(const f32x4*)&sS[ib + 2][rb];
        const f32x4 sv3 = *(const f32x4*)&sS[ib + 3][rb];
#pragma unroll
        for (int rr = 0; rr < 4; ++rr) {
          const f32x4 g4 = *(const f32x4*)(G + (size_t)(rb + rr) * NN + c);
          a0 += sv0[rr] * g4;
          a1 += sv1[rr] * g4;
          a2 += sv2[rr] * g4;
          a3 += sv3[rr] * g4;
        }
      }
#define STORE_ROW(jj, av) {                                        \
      const f32x4 hv = (av) + b1v;                                 \
      bf16x4 o;                                                    \
      o[0] = (bf16)fmaxf(hv[0], 0.f); o[1] = (bf16)fmaxf(hv[1], 0.f); \
      o[2] = (bf16)fmaxf(hv[2], 0.f); o[3] = (bf16)fmaxf(hv[3], 0.f); \
      *(bf16x4*)(hout + (size_t)(r0 + ib + (jj)) * NN + c) = o; }
      STORE_ROW(0, a0) STORE_ROW(1, a1) STORE_ROW(2, a2) STORE_ROW(3, a3)
#undef STORE_ROW
    }
  }
}

// ---------------------------------------------------------------------------
// Kernel 2: W2t[o][n] = (bf16)W2[n][o]   (64x64 LDS tile transpose)
__global__ __launch_bounds__(256) void k2_w2t(
    const float* __restrict__ W2, bf16* __restrict__ W2t)
{
  __shared__ float tile[64][65];   // +1 pad: conflict-free-ish both phases
  const int t    = threadIdx.x;
  const int kb   = (blockIdx.x >> 6) * 64;
  const int ob   = (blockIdx.x & 63) * 64;
  const int row  = t >> 4;
  const int col4 = (t & 15) * 4;
#pragma unroll
  for (int p = 0; p < 4; ++p) {
    const f32x4 v = *(const f32x4*)(W2 + (size_t)(kb + p*16 + row) * KOUT + ob + col4);
    tile[p*16 + row][col4 + 0] = v[0];
    tile[p*16 + row][col4 + 1] = v[1];
    tile[p*16 + row][col4 + 2] = v[2];
    tile[p*16 + row][col4 + 3] = v[3];
  }
  __syncthreads();
  const int jj0 = t >> 4;
  const int ii4 = (t & 15) * 4;
#pragma unroll
  for (int p = 0; p < 4; ++p) {
    const int jj = p*16 + jj0;
    bf16x4 o;
    o[0] = (bf16)tile[ii4 + 0][jj];
    o[1] = (bf16)tile[ii4 + 1][jj];
    o[2] = (bf16)tile[ii4 + 2][jj];
    o[3] = (bf16)tile[ii4 + 3][jj];
    *(bf16x4*)(W2t + (size_t)(ob + jj) * NN + kb + ii4) = o;
  }
}

// ---------------------------------------------------------------------------
// Kernel 3: C[M][N] = A[M][K] * Bt[N][K]^T + b2   (bf16 in, f32 out)
// m97 structure: 128x128 tile, BK=32, 4 waves (2x2), global_load_lds w=16,
// ds_read_b128 fragments, v_mfma_f32_16x16x32_bf16, XCD-swizzled blockIdx.
#define BM 128
#define BN 128
#define BK 32

__global__ __launch_bounds__(256) void k3_gemm(
    const bf16* __restrict__ A, const bf16* __restrict__ Bt,
    const float* __restrict__ b2, float* __restrict__ C)
{
  __shared__ __align__(16) bf16 As[BM * BK];
  __shared__ __align__(16) bf16 Bs[BN * BK];

  // bijective XCD swizzle: 2048 blocks, 2048 % 8 == 0
  const int bid = blockIdx.x;
  const int swz = (bid & 7) * 256 + (bid >> 3);
  const int tm  = swz >> 5;             // 64 M-tiles
  const int tn  = swz & 31;             // 32 N-tiles
  const int brow = tm * BM, bcol = tn * BN;

  const int t    = threadIdx.x;
  const int lane = t & 63;
  const int wave = t >> 6;
  const int wr   = wave >> 1, wc = wave & 1;

  const int srow = t >> 2;              // staging row (0..63) per issue
  const int scol = (t & 3) * 8;         // staging k-offset (elements)

  f32x4 acc[4][4];
#pragma unroll
  for (int m = 0; m < 4; ++m)
#pragma unroll
    for (int n = 0; n < 4; ++n) acc[m][n] = (f32x4){0.f,0.f,0.f,0.f};

  const int fr = lane & 15;             // row (A) / col (B) within fragment
  const int fk = lane >> 4;             // k-group

  for (int kt = 0; kt < NN; kt += BK) {
#pragma unroll
    for (int s = 0; s < 2; ++s) {
      gload_lds16(A  + (size_t)(brow + srow + s*64) * NN + kt + scol,
                  (bf16*)((char*)As + t*16 + s*4096));
      gload_lds16(Bt + (size_t)(bcol + srow + s*64) * NN + kt + scol,
                  (bf16*)((char*)Bs + t*16 + s*4096));
    }
    __syncthreads();   // compiler drains vmcnt before s_barrier

    bf16x8 af[4], bfr[4];
#pragma unroll
    for (int m = 0; m < 4; ++m)
      af[m]  = *(const bf16x8*)(As + (wr*64 + m*16 + fr) * BK + fk*8);
#pragma unroll
    for (int n = 0; n < 4; ++n)
      bfr[n] = *(const bf16x8*)(Bs + (wc*64 + n*16 + fr) * BK + fk*8);

#pragma unroll
    for (int m = 0; m < 4; ++m)
#pragma unroll
      for (int n = 0; n < 4; ++n)
        acc[m][n] = __builtin_amdgcn_mfma_f32_16x16x32_bf16(
            af[m], bfr[n], acc[m][n], 0, 0, 0);
    __syncthreads();
  }

  // epilogue: C layout col = lane&15, row = (lane>>4)*4 + reg
#pragma unroll
  for (int n = 0; n < 4; ++n) {
    const int col  = bcol + wc*64 + n*16 + fr;
    const float bias = b2[col];
#pragma unroll
    for (int m = 0; m < 4; ++m) {
      const int row0 = brow + wr*64 + m*16 + fk*4;
#pragma unroll
      for (int q = 0; q < 4; ++q)
        C[(size_t)(row0 + q) * KOUT + col] = acc[m][n][q] + bias;
    }
  }
}

// ---------------------------------------------------------------------------
extern "C" void kernel_launch(void* const* d_in, const int* in_sizes, int n_in,
                              void* d_out, int out_size, void* d_ws, size_t ws_size,
                              hipStream_t stream) {
  const float* x  = (const float*)d_in[0];
  const float* G  = (const float*)d_in[1];
  const float* H  = (const float*)d_in[2];
  const float* b1 = (const float*)d_in[3];
  const float* W2 = (const float*)d_in[4];
  const float* b2 = (const float*)d_in[5];
  float* y = (float*)d_out;

  bf16* hbuf = (bf16*)d_ws;                       // 8192*4096*2 = 64 MiB
  bf16* w2t  = hbuf + (size_t)MB * NN;            // 4096*4096*2 = 32 MiB

  hipLaunchKernelGGL(k1_lowrank, dim3(MB / 16), dim3(256), 0, stream,
                     x, G, H, b1, hbuf);
  hipLaunchKernelGGL(k2_w2t, dim3(64 * 64), dim3(256), 0, stream, W2, w2t);
  hipLaunchKernelGGL(k3_gemm, dim3((MB / BM) * (KOUT / BN)), dim3(256), 0, stream,
                     hbuf, w2t, b2, y);
}

// Round 2
// 369.378 us; speedup vs baseline: 1.1772x; 1.1772x over previous
//
#include <hip/hip_runtime.h>
#include <hip/hip_bf16.h>
#include <cstdint>
#include <cstddef>

typedef __bf16 bf16;
typedef __bf16 bf16x4 __attribute__((ext_vector_type(4)));
typedef __bf16 bf16x8 __attribute__((ext_vector_type(8)));
typedef float  f32x4  __attribute__((ext_vector_type(4)));

#define MB   8192
#define NN   4096
#define RR   16
#define KOUT 4096

// ---------------------------------------------------------------------------
// async global->LDS (16B per lane). LDS dest: wave-uniform base + lane*16.
__device__ __forceinline__ void gload_lds16(const bf16* g, bf16* l) {
  __builtin_amdgcn_global_load_lds(
      (const __attribute__((address_space(1))) void*)g,
      (__attribute__((address_space(3))) void*)l, 16, 0, 0);
}

// ---------------------------------------------------------------------------
// Kernel 1: per block = 16 rows of x.
__global__ __launch_bounds__(256) void k1_lowrank(
    const float* __restrict__ x, const float* __restrict__ G,
    const float* __restrict__ H, const float* __restrict__ b1,
    bf16* __restrict__ hout)
{
  __shared__ float sS[16][16];
  const int t    = threadIdx.x;
  const int lane = t & 63;
  const int wave = t >> 6;
  const int r0   = blockIdx.x * 16;
  const int i0   = wave * 4;

  float acc[4][RR];
#pragma unroll
  for (int j = 0; j < 4; ++j)
#pragma unroll
    for (int r = 0; r < RR; ++r) acc[j][r] = 0.f;

  for (int kt = 0; kt < NN; kt += 256) {
    const int k = kt + lane * 4;
    f32x4 xv[4];
#pragma unroll
    for (int j = 0; j < 4; ++j)
      xv[j] = *(const f32x4*)(x + (size_t)(r0 + i0 + j) * NN + k);
#pragma unroll
    for (int r = 0; r < RR; ++r) {
      const f32x4 hv = *(const f32x4*)(H + (size_t)r * NN + k);
#pragma unroll
      for (int j = 0; j < 4; ++j) {
        acc[j][r] = fmaf(xv[j].x, hv.x, acc[j][r]);
        acc[j][r] = fmaf(xv[j].y, hv.y, acc[j][r]);
        acc[j][r] = fmaf(xv[j].z, hv.z, acc[j][r]);
        acc[j][r] = fmaf(xv[j].w, hv.w, acc[j][r]);
      }
    }
  }

#pragma unroll
  for (int j = 0; j < 4; ++j)
#pragma unroll
    for (int r = 0; r < RR; ++r) {
      float v = acc[j][r];
#pragma unroll
      for (int off = 32; off >= 1; off >>= 1) v += __shfl_xor(v, off, 64);
      acc[j][r] = v;
    }
  if (lane == 0) {
#pragma unroll
    for (int j = 0; j < 4; ++j)
#pragma unroll
      for (int r = 0; r < RR; ++r) sS[i0 + j][r] = acc[j][r];
  }
  __syncthreads();

#pragma unroll
  for (int chunk = 0; chunk < 4; ++chunk) {
    const int c = chunk * 1024 + t * 4;
    const f32x4 b1v = *(const f32x4*)(b1 + c);
#pragma unroll
    for (int ib = 0; ib < 16; ib += 4) {
      f32x4 a0 = {0.f,0.f,0.f,0.f}, a1 = a0, a2 = a0, a3 = a0;
#pragma unroll
      for (int rb = 0; rb < 16; rb += 4) {
        const f32x4 sv0 = *(const f32x4*)&sS[ib + 0][rb];
        const f32x4 sv1 = *(const f32x4*)&sS[ib + 1][rb];
        const f32x4 sv2 = *(const f32x4*)&sS[ib + 2][rb];
        const f32x4 sv3 = *(const f32x4*)&sS[ib + 3][rb];
#pragma unroll
        for (int rr = 0; rr < 4; ++rr) {
          const f32x4 g4 = *(const f32x4*)(G + (size_t)(rb + rr) * NN + c);
          a0 += sv0[rr] * g4;
          a1 += sv1[rr] * g4;
          a2 += sv2[rr] * g4;
          a3 += sv3[rr] * g4;
        }
      }
#define STORE_ROW(jj, av) {                                        \
      const f32x4 hv = (av) + b1v;                                 \
      bf16x4 o;                                                    \
      o[0] = (bf16)fmaxf(hv[0], 0.f); o[1] = (bf16)fmaxf(hv[1], 0.f); \
      o[2] = (bf16)fmaxf(hv[2], 0.f); o[3] = (bf16)fmaxf(hv[3], 0.f); \
      *(bf16x4*)(hout + (size_t)(r0 + ib + (jj)) * NN + c) = o; }
      STORE_ROW(0, a0) STORE_ROW(1, a1) STORE_ROW(2, a2) STORE_ROW(3, a3)
#undef STORE_ROW
    }
  }
}

// ---------------------------------------------------------------------------
// Kernel 2: W2t[o][n] = (bf16)W2[n][o]
__global__ __launch_bounds__(256) void k2_w2t(
    const float* __restrict__ W2, bf16* __restrict__ W2t)
{
  __shared__ float tile[64][65];
  const int t    = threadIdx.x;
  const int kb   = (blockIdx.x >> 6) * 64;
  const int ob   = (blockIdx.x & 63) * 64;
  const int row  = t >> 4;
  const int col4 = (t & 15) * 4;
#pragma unroll
  for (int p = 0; p < 4; ++p) {
    const f32x4 v = *(const f32x4*)(W2 + (size_t)(kb + p*16 + row) * KOUT + ob + col4);
    tile[p*16 + row][col4 + 0] = v[0];
    tile[p*16 + row][col4 + 1] = v[1];
    tile[p*16 + row][col4 + 2] = v[2];
    tile[p*16 + row][col4 + 3] = v[3];
  }
  __syncthreads();
  const int jj0 = t >> 4;
  const int ii4 = (t & 15) * 4;
#pragma unroll
  for (int p = 0; p < 4; ++p) {
    const int jj = p*16 + jj0;
    bf16x4 o;
    o[0] = (bf16)tile[ii4 + 0][jj];
    o[1] = (bf16)tile[ii4 + 1][jj];
    o[2] = (bf16)tile[ii4 + 2][jj];
    o[3] = (bf16)tile[ii4 + 3][jj];
    *(bf16x4*)(W2t + (size_t)(ob + jj) * NN + kb + ii4) = o;
  }
}

// ---------------------------------------------------------------------------
// Kernel 3: 256x256 8-phase bf16 GEMM (T2+T3+T4+T5 template).
// C[M][N] = A[M][K] * Bt[N][K]^T + b2.  512 thr = 8 waves (2M x 4N).
// LDS 128 KiB: A[2buf][2half][128][64] bf16 + B same, st_16x32 swizzled.
// Per K-tile (BK=64): 4 phases; stage 1 half-tile/phase; vmcnt(6) once/tile.
#define NT 64   // K tiles = 4096/64

__global__ __launch_bounds__(512, 1) void k3_gemm256(
    const bf16* __restrict__ A, const bf16* __restrict__ Bt,
    const float* __restrict__ b2, float* __restrict__ C)
{
  extern __shared__ __align__(16) char smem[];
  bf16* lds = (bf16*)smem;
  const char* ldsc = (const char*)smem;

  // bijective XCD swizzle: 512 blocks, 512 % 8 == 0
  const int bid = blockIdx.x;
  const int swz = (bid & 7) * 64 + (bid >> 3);
  const int tm = swz >> 4, tn = swz & 15;       // 32 x 16 tiles
  const int brow = tm * 256, bcol = tn * 256;

  const int t    = threadIdx.x;
  const int lane = t & 63;
  const int wave = t >> 6;
  const int wr   = wave >> 2;   // 0..1  (M)
  const int wc   = wave & 3;    // 0..3  (N)
  const int fr   = lane & 15;
  const int fk   = lane >> 4;

  // staging source coords: linear LDS dest byte d -> logical byte l = swz(d)
  int srow[2], scol[2];
#pragma unroll
  for (int i = 0; i < 2; ++i) {
    const int d = (i * 512 + t) * 16;
    const int l = d ^ (((d >> 9) & 1) << 5);
    srow[i] = l >> 7;            // row within 128-row half
    scol[i] = (l & 127) >> 1;    // element col within 64
  }
  const bf16* gA0 = A  + (size_t)brow * NN;
  const bf16* gA1 = A  + (size_t)(brow + 128) * NN;
  const bf16* gB0 = Bt + (size_t)bcol * NN;
  const bf16* gB1 = Bt + (size_t)(bcol + 128) * NN;

  // A region elem offs: buf*16384 + half*8192 ; B adds 32768
  auto stage = [&](const bf16* g, int regionElem, int kt) {
#pragma unroll
    for (int i = 0; i < 2; ++i)
      gload_lds16(g + (size_t)srow[i] * NN + kt + scol[i],
                  lds + regionElem + i * 4096 + t * 8);
  };

  // ds_read byte offset within a half-tile (swizzled)
  auto offA = [&](int mi, int kk) -> int {
    const int row = mi * 32 + wr * 16 + fr;
    const int b = row * 128 + kk * 64 + fk * 16;
    return b ^ (((b >> 9) & 1) << 5);
  };
  auto offB = [&](int nj, int kk) -> int {
    const int row = nj * 64 + wc * 16 + fr;
    const int b = row * 128 + kk * 64 + fk * 16;
    return b ^ (((b >> 9) & 1) << 5);
  };

  f32x4 acc[8][4];
#pragma unroll
  for (int m = 0; m < 8; ++m)
#pragma unroll
    for (int n = 0; n < 4; ++n) acc[m][n] = (f32x4){0.f,0.f,0.f,0.f};

  bf16x8 a[8], b0[4], b1[4];

  // ---- prologue: tile0 {A0,B0,B1,A1}, tile1 {A0,B0,B1}
  stage(gA0, 0,           0); stage(gB0, 32768,       0);
  stage(gB1, 32768+8192,  0); stage(gA1, 8192,        0);
  asm volatile("s_waitcnt vmcnt(4)" ::: "memory");
  stage(gA0, 16384,       64); stage(gB0, 32768+16384, 64);
  stage(gB1, 32768+16384+8192, 64);
  asm volatile("s_waitcnt vmcnt(6)" ::: "memory");
  __builtin_amdgcn_s_barrier();

#pragma unroll 1
  for (int u0 = 0; u0 < NT; u0 += 2) {
#pragma unroll
    for (int hi = 0; hi < 2; ++hi) {
      const int u   = u0 + hi;
      const int buf = hi;                        // u & 1
      const char* pa = ldsc + buf * 32768;           // A half0 bytes
      const char* pb = ldsc + 65536 + buf * 32768;   // B half0 bytes
      const int obuf = buf ^ 1;

      // ======== phase 1: read A-mh0 (8) + B-nh0 (4); stage (u+1)A1
#pragma unroll
      for (int mi = 0; mi < 4; ++mi)
#pragma unroll
        for (int kk = 0; kk < 2; ++kk)
          a[mi*2+kk] = *(const bf16x8*)(pa + offA(mi, kk));
#pragma unroll
      for (int nj = 0; nj < 2; ++nj)
#pragma unroll
        for (int kk = 0; kk < 2; ++kk)
          b0[nj*2+kk] = *(const bf16x8*)(pb + offB(nj, kk));
      if (u < NT-1) stage(gA1, obuf*16384 + 8192, (u+1)*64);
      asm volatile("s_waitcnt lgkmcnt(8)" ::: "memory");
      __builtin_amdgcn_s_barrier();
      asm volatile("s_waitcnt lgkmcnt(0)" ::: "memory");
      __builtin_amdgcn_sched_barrier(0);
      __builtin_amdgcn_s_setprio(1);
#pragma unroll
      for (int mi = 0; mi < 4; ++mi)
#pragma unroll
        for (int nj = 0; nj < 2; ++nj)
#pragma unroll
          for (int kk = 0; kk < 2; ++kk)
            acc[mi][nj] = __builtin_amdgcn_mfma_f32_16x16x32_bf16(
                a[mi*2+kk], b0[nj*2+kk], acc[mi][nj], 0, 0, 0);
      __builtin_amdgcn_s_setprio(0);
      __builtin_amdgcn_s_barrier();

      // ======== phase 2: read B-nh1 (4); stage (u+2)A0
#pragma unroll
      for (int nj = 0; nj < 2; ++nj)
#pragma unroll
        for (int kk = 0; kk < 2; ++kk)
          b1[nj*2+kk] = *(const bf16x8*)(pb + 16384 + offB(nj, kk));
      if (u < NT-2) stage(gA0, buf*16384, (u+2)*64);
      __builtin_amdgcn_s_barrier();
      asm volatile("s_waitcnt lgkmcnt(0)" ::: "memory");
      __builtin_amdgcn_sched_barrier(0);
      __builtin_amdgcn_s_setprio(1);
#pragma unroll
      for (int mi = 0; mi < 4; ++mi)
#pragma unroll
        for (int nj = 0; nj < 2; ++nj)
#pragma unroll
          for (int kk = 0; kk < 2; ++kk)
            acc[mi][2+nj] = __builtin_amdgcn_mfma_f32_16x16x32_bf16(
                a[mi*2+kk], b1[nj*2+kk], acc[mi][2+nj], 0, 0, 0);
      __builtin_amdgcn_s_setprio(0);
      __builtin_amdgcn_s_barrier();

      // ======== phase 3: read A-mh1 (8); stage (u+2)B0
#pragma unroll
      for (int mi = 0; mi < 4; ++mi)
#pragma unroll
        for (int kk = 0; kk < 2; ++kk)
          a[mi*2+kk] = *(const bf16x8*)(pa + 16384 + offA(mi, kk));
      if (u < NT-2) stage(gB0, 32768 + buf*16384, (u+2)*64);
      __builtin_amdgcn_s_barrier();
      asm volatile("s_waitcnt lgkmcnt(0)" ::: "memory");
      __builtin_amdgcn_sched_barrier(0);
      __builtin_amdgcn_s_setprio(1);
#pragma unroll
      for (int mi = 0; mi < 4; ++mi)
#pragma unroll
        for (int nj = 0; nj < 2; ++nj)
#pragma unroll
          for (int kk = 0; kk < 2; ++kk)
            acc[4+mi][2+nj] = __builtin_amdgcn_mfma_f32_16x16x32_bf16(
                a[mi*2+kk], b1[nj*2+kk], acc[4+mi][2+nj], 0, 0, 0);
      __builtin_amdgcn_s_setprio(0);
      __builtin_amdgcn_s_barrier();

      // ======== phase 4: no reads; stage (u+2)B1; vmcnt at tile end
      if (u < NT-2) stage(gB1, 32768 + buf*16384 + 8192, (u+2)*64);
      __builtin_amdgcn_s_barrier();
      __builtin_amdgcn_s_setprio(1);
#pragma unroll
      for (int mi = 0; mi < 4; ++mi)
#pragma unroll
        for (int nj = 0; nj < 2; ++nj)
#pragma unroll
          for (int kk = 0; kk < 2; ++kk)
            acc[4+mi][nj] = __builtin_amdgcn_mfma_f32_16x16x32_bf16(
                a[mi*2+kk], b0[nj*2+kk], acc[4+mi][nj], 0, 0, 0);
      __builtin_amdgcn_s_setprio(0);
      if (u < NT-2)       { asm volatile("s_waitcnt vmcnt(6)" ::: "memory"); }
      else if (u == NT-2) { asm volatile("s_waitcnt vmcnt(0)" ::: "memory"); }
      __builtin_amdgcn_s_barrier();
    }
  }

  // epilogue: D layout col = fr, row = fk*4 + q
#pragma unroll
  for (int n = 0; n < 4; ++n) {
    const int col = bcol + n * 64 + wc * 16 + fr;
    const float bias = b2[col];
#pragma unroll
    for (int m = 0; m < 8; ++m) {
      const int row0 = brow + m * 32 + wr * 16 + fk * 4;
      float* cp = C + (size_t)row0 * KOUT + col;
#pragma unroll
      for (int q = 0; q < 4; ++q)
        cp[(size_t)q * KOUT] = acc[m][n][q] + bias;
    }
  }
}

// ---------------------------------------------------------------------------
extern "C" void kernel_launch(void* const* d_in, const int* in_sizes, int n_in,
                              void* d_out, int out_size, void* d_ws, size_t ws_size,
                              hipStream_t stream) {
  const float* x  = (const float*)d_in[0];
  const float* G  = (const float*)d_in[1];
  const float* H  = (const float*)d_in[2];
  const float* b1 = (const float*)d_in[3];
  const float* W2 = (const float*)d_in[4];
  const float* b2 = (const float*)d_in[5];
  float* y = (float*)d_out;

  bf16* hbuf = (bf16*)d_ws;                       // 8192*4096*2 = 64 MiB
  bf16* w2t  = hbuf + (size_t)MB * NN;            // 4096*4096*2 = 32 MiB

  hipFuncSetAttribute((const void*)k3_gemm256,
                      hipFuncAttributeMaxDynamicSharedMemorySize, 131072);

  hipLaunchKernelGGL(k1_lowrank, dim3(MB / 16), dim3(256), 0, stream,
                     x, G, H, b1, hbuf);
  hipLaunchKernelGGL(k2_w2t, dim3(64 * 64), dim3(256), 0, stream, W2, w2t);
  hipLaunchKernelGGL(k3_gemm256, dim3((MB/256) * (KOUT/256)), dim3(512), 131072,
                     stream, hbuf, w2t, b2, y);
}

// Round 3
// 344.528 us; speedup vs baseline: 1.2621x; 1.0721x over previous
//
#include <hip/hip_runtime.h>
#include <hip/hip_bf16.h>
#include <cstdint>
#include <cstddef>

typedef __bf16 bf16;
typedef __bf16 bf16x4 __attribute__((ext_vector_type(4)));
typedef __bf16 bf16x8 __attribute__((ext_vector_type(8)));
typedef float  f32x4  __attribute__((ext_vector_type(4)));

#define MB   8192
#define NN   4096
#define RR   16
#define KOUT 4096

// ---------------------------------------------------------------------------
// async global->LDS (16B per lane). LDS dest: wave-uniform base + lane*16.
__device__ __forceinline__ void gload_lds16(const bf16* g, bf16* l) {
  __builtin_amdgcn_global_load_lds(
      (const __attribute__((address_space(1))) void*)g,
      (__attribute__((address_space(3))) void*)l, 16, 0, 0);
}

// ---------------------------------------------------------------------------
// Kernel 1: per block = 16 rows of x.
__global__ __launch_bounds__(256) void k1_lowrank(
    const float* __restrict__ x, const float* __restrict__ G,
    const float* __restrict__ H, const float* __restrict__ b1,
    bf16* __restrict__ hout)
{
  __shared__ float sS[16][16];
  const int t    = threadIdx.x;
  const int lane = t & 63;
  const int wave = t >> 6;
  const int r0   = blockIdx.x * 16;
  const int i0   = wave * 4;

  float acc[4][RR];
#pragma unroll
  for (int j = 0; j < 4; ++j)
#pragma unroll
    for (int r = 0; r < RR; ++r) acc[j][r] = 0.f;

  for (int kt = 0; kt < NN; kt += 256) {
    const int k = kt + lane * 4;
    f32x4 xv[4];
#pragma unroll
    for (int j = 0; j < 4; ++j)
      xv[j] = *(const f32x4*)(x + (size_t)(r0 + i0 + j) * NN + k);
#pragma unroll
    for (int r = 0; r < RR; ++r) {
      const f32x4 hv = *(const f32x4*)(H + (size_t)r * NN + k);
#pragma unroll
      for (int j = 0; j < 4; ++j) {
        acc[j][r] = fmaf(xv[j].x, hv.x, acc[j][r]);
        acc[j][r] = fmaf(xv[j].y, hv.y, acc[j][r]);
        acc[j][r] = fmaf(xv[j].z, hv.z, acc[j][r]);
        acc[j][r] = fmaf(xv[j].w, hv.w, acc[j][r]);
      }
    }
  }

#pragma unroll
  for (int j = 0; j < 4; ++j)
#pragma unroll
    for (int r = 0; r < RR; ++r) {
      float v = acc[j][r];
#pragma unroll
      for (int off = 32; off >= 1; off >>= 1) v += __shfl_xor(v, off, 64);
      acc[j][r] = v;
    }
  if (lane == 0) {
#pragma unroll
    for (int j = 0; j < 4; ++j)
#pragma unroll
      for (int r = 0; r < RR; ++r) sS[i0 + j][r] = acc[j][r];
  }
  __syncthreads();

#pragma unroll
  for (int chunk = 0; chunk < 4; ++chunk) {
    const int c = chunk * 1024 + t * 4;
    const f32x4 b1v = *(const f32x4*)(b1 + c);
#pragma unroll
    for (int ib = 0; ib < 16; ib += 4) {
      f32x4 a0 = {0.f,0.f,0.f,0.f}, a1 = a0, a2 = a0, a3 = a0;
#pragma unroll
      for (int rb = 0; rb < 16; rb += 4) {
        const f32x4 sv0 = *(const f32x4*)&sS[ib + 0][rb];
        const f32x4 sv1 = *(const f32x4*)&sS[ib + 1][rb];
        const f32x4 sv2 = *(const f32x4*)&sS[ib + 2][rb];
        const f32x4 sv3 = *(const f32x4*)&sS[ib + 3][rb];
#pragma unroll
        for (int rr = 0; rr < 4; ++rr) {
          const f32x4 g4 = *(const f32x4*)(G + (size_t)(rb + rr) * NN + c);
          a0 += sv0[rr] * g4;
          a1 += sv1[rr] * g4;
          a2 += sv2[rr] * g4;
          a3 += sv3[rr] * g4;
        }
      }
#define STORE_ROW(jj, av) {                                        \
      const f32x4 hv = (av) + b1v;                                 \
      bf16x4 o;                                                    \
      o[0] = (bf16)fmaxf(hv[0], 0.f); o[1] = (bf16)fmaxf(hv[1], 0.f); \
      o[2] = (bf16)fmaxf(hv[2], 0.f); o[3] = (bf16)fmaxf(hv[3], 0.f); \
      *(bf16x4*)(hout + (size_t)(r0 + ib + (jj)) * NN + c) = o; }
      STORE_ROW(0, a0) STORE_ROW(1, a1) STORE_ROW(2, a2) STORE_ROW(3, a3)
#undef STORE_ROW
    }
  }
}

// ---------------------------------------------------------------------------
// Kernel 2: W2t[o][n] = (bf16)W2[n][o]
__global__ __launch_bounds__(256) void k2_w2t(
    const float* __restrict__ W2, bf16* __restrict__ W2t)
{
  __shared__ float tile[64][65];
  const int t    = threadIdx.x;
  const int kb   = (blockIdx.x >> 6) * 64;
  const int ob   = (blockIdx.x & 63) * 64;
  const int row  = t >> 4;
  const int col4 = (t & 15) * 4;
#pragma unroll
  for (int p = 0; p < 4; ++p) {
    const f32x4 v = *(const f32x4*)(W2 + (size_t)(kb + p*16 + row) * KOUT + ob + col4);
    tile[p*16 + row][col4 + 0] = v[0];
    tile[p*16 + row][col4 + 1] = v[1];
    tile[p*16 + row][col4 + 2] = v[2];
    tile[p*16 + row][col4 + 3] = v[3];
  }
  __syncthreads();
  const int jj0 = t >> 4;
  const int ii4 = (t & 15) * 4;
#pragma unroll
  for (int p = 0; p < 4; ++p) {
    const int jj = p*16 + jj0;
    bf16x4 o;
    o[0] = (bf16)tile[ii4 + 0][jj];
    o[1] = (bf16)tile[ii4 + 1][jj];
    o[2] = (bf16)tile[ii4 + 2][jj];
    o[3] = (bf16)tile[ii4 + 3][jj];
    *(bf16x4*)(W2t + (size_t)(ob + jj) * NN + kb + ii4) = o;
  }
}

// ---------------------------------------------------------------------------
// Kernel 3: 256x256 8-phase bf16 GEMM (T2+T3+T4+T5 template).
// C[M][N] = A[M][K] * Bt[N][K]^T + b2.  512 thr = 8 waves (2M x 4N).
// LDS 128 KiB: A[2buf][2half][128 rows][128 B] + B same.
// Swizzle (row-major 128B rows, column-slice ds_read_b128):
//   byte ^= (row&7)<<4  -> each 16-lane group spreads over all 8 16B slots.
// Write side: gload_lds dest linear, global SOURCE pre-inverse-swizzled.
// Per K-tile (BK=64): 4 phases; stage 1 half-tile/phase; vmcnt(6) once/tile.
#define NT 64   // K tiles = 4096/64

__global__ __launch_bounds__(512, 1) void k3_gemm256(
    const bf16* __restrict__ A, const bf16* __restrict__ Bt,
    const float* __restrict__ b2, float* __restrict__ C)
{
  extern __shared__ __align__(16) char smem[];
  bf16* lds = (bf16*)smem;
  const char* ldsc = (const char*)smem;

  // bijective XCD swizzle: 512 blocks, 512 % 8 == 0
  const int bid = blockIdx.x;
  const int swz = (bid & 7) * 64 + (bid >> 3);
  const int tm = swz >> 4, tn = swz & 15;       // 32 x 16 tiles
  const int brow = tm * 256, bcol = tn * 256;

  const int t    = threadIdx.x;
  const int lane = t & 63;
  const int wave = t >> 6;
  const int wr   = wave >> 2;   // 0..1  (M)
  const int wc   = wave & 3;    // 0..3  (N)
  const int fr   = lane & 15;
  const int fk   = lane >> 4;

  // staging source coords: linear LDS dest byte d holds logical byte
  // l = d ^ ((row&7)<<4)  (involution within each 128B row; row = d>>7)
  int srow[2], scol[2];
#pragma unroll
  for (int i = 0; i < 2; ++i) {
    const int d   = i * 8192 + t * 16;       // dest byte within 16 KiB half
    const int row = d >> 7;                  // 0..127
    const int l   = d ^ ((row & 7) << 4);
    srow[i] = row;
    scol[i] = (l & 127) >> 1;                // element col 0..63
  }
  const bf16* gA0 = A  + (size_t)brow * NN;
  const bf16* gA1 = A  + (size_t)(brow + 128) * NN;
  const bf16* gB0 = Bt + (size_t)bcol * NN;
  const bf16* gB1 = Bt + (size_t)(bcol + 128) * NN;

  // A region elem offs: buf*16384 + half*8192 ; B adds 32768
  auto stage = [&](const bf16* g, int regionElem, int kt) {
#pragma unroll
    for (int i = 0; i < 2; ++i)
      gload_lds16(g + (size_t)srow[i] * NN + kt + scol[i],
                  lds + regionElem + i * 4096 + t * 8);
  };

  // ds_read byte offset within a half-tile (swizzled)
  auto offA = [&](int mi, int kk) -> int {
    const int row = mi * 32 + wr * 16 + fr;
    const int b = row * 128 + kk * 64 + fk * 16;
    return b ^ ((row & 7) << 4);
  };
  auto offB = [&](int nj, int kk) -> int {
    const int row = nj * 64 + wc * 16 + fr;
    const int b = row * 128 + kk * 64 + fk * 16;
    return b ^ ((row & 7) << 4);
  };

  f32x4 acc[8][4];
#pragma unroll
  for (int m = 0; m < 8; ++m)
#pragma unroll
    for (int n = 0; n < 4; ++n) acc[m][n] = (f32x4){0.f,0.f,0.f,0.f};

  bf16x8 a[8], b0[4], b1[4];

  // ---- prologue: tile0 {A0,B0,B1,A1}, tile1 {A0,B0,B1}
  stage(gA0, 0,           0); stage(gB0, 32768,       0);
  stage(gB1, 32768+8192,  0); stage(gA1, 8192,        0);
  asm volatile("s_waitcnt vmcnt(4)" ::: "memory");
  stage(gA0, 16384,       64); stage(gB0, 32768+16384, 64);
  stage(gB1, 32768+16384+8192, 64);
  asm volatile("s_waitcnt vmcnt(6)" ::: "memory");
  __builtin_amdgcn_s_barrier();

#pragma unroll 1
  for (int u0 = 0; u0 < NT; u0 += 2) {
#pragma unroll
    for (int hi = 0; hi < 2; ++hi) {
      const int u   = u0 + hi;
      const int buf = hi;                        // u & 1
      const char* pa = ldsc + buf * 32768;           // A half0 bytes
      const char* pb = ldsc + 65536 + buf * 32768;   // B half0 bytes
      const int obuf = buf ^ 1;

      // ======== phase 1: read A-mh0 (8) + B-nh0 (4); stage (u+1)A1
#pragma unroll
      for (int mi = 0; mi < 4; ++mi)
#pragma unroll
        for (int kk = 0; kk < 2; ++kk)
          a[mi*2+kk] = *(const bf16x8*)(pa + offA(mi, kk));
#pragma unroll
      for (int nj = 0; nj < 2; ++nj)
#pragma unroll
        for (int kk = 0; kk < 2; ++kk)
          b0[nj*2+kk] = *(const bf16x8*)(pb + offB(nj, kk));
      if (u < NT-1) stage(gA1, obuf*16384 + 8192, (u+1)*64);
      asm volatile("s_waitcnt lgkmcnt(8)" ::: "memory");
      __builtin_amdgcn_s_barrier();
      asm volatile("s_waitcnt lgkmcnt(0)" ::: "memory");
      __builtin_amdgcn_sched_barrier(0);
      __builtin_amdgcn_s_setprio(1);
#pragma unroll
      for (int mi = 0; mi < 4; ++mi)
#pragma unroll
        for (int nj = 0; nj < 2; ++nj)
#pragma unroll
          for (int kk = 0; kk < 2; ++kk)
            acc[mi][nj] = __builtin_amdgcn_mfma_f32_16x16x32_bf16(
                a[mi*2+kk], b0[nj*2+kk], acc[mi][nj], 0, 0, 0);
      __builtin_amdgcn_s_setprio(0);
      __builtin_amdgcn_s_barrier();

      // ======== phase 2: read B-nh1 (4); stage (u+2)A0
#pragma unroll
      for (int nj = 0; nj < 2; ++nj)
#pragma unroll
        for (int kk = 0; kk < 2; ++kk)
          b1[nj*2+kk] = *(const bf16x8*)(pb + 16384 + offB(nj, kk));
      if (u < NT-2) stage(gA0, buf*16384, (u+2)*64);
      __builtin_amdgcn_s_barrier();
      asm volatile("s_waitcnt lgkmcnt(0)" ::: "memory");
      __builtin_amdgcn_sched_barrier(0);
      __builtin_amdgcn_s_setprio(1);
#pragma unroll
      for (int mi = 0; mi < 4; ++mi)
#pragma unroll
        for (int nj = 0; nj < 2; ++nj)
#pragma unroll
          for (int kk = 0; kk < 2; ++kk)
            acc[mi][2+nj] = __builtin_amdgcn_mfma_f32_16x16x32_bf16(
                a[mi*2+kk], b1[nj*2+kk], acc[mi][2+nj], 0, 0, 0);
      __builtin_amdgcn_s_setprio(0);
      __builtin_amdgcn_s_barrier();

      // ======== phase 3: read A-mh1 (8); stage (u+2)B0
#pragma unroll
      for (int mi = 0; mi < 4; ++mi)
#pragma unroll
        for (int kk = 0; kk < 2; ++kk)
          a[mi*2+kk] = *(const bf16x8*)(pa + 16384 + offA(mi, kk));
      if (u < NT-2) stage(gB0, 32768 + buf*16384, (u+2)*64);
      __builtin_amdgcn_s_barrier();
      asm volatile("s_waitcnt lgkmcnt(0)" ::: "memory");
      __builtin_amdgcn_sched_barrier(0);
      __builtin_amdgcn_s_setprio(1);
#pragma unroll
      for (int mi = 0; mi < 4; ++mi)
#pragma unroll
        for (int nj = 0; nj < 2; ++nj)
#pragma unroll
          for (int kk = 0; kk < 2; ++kk)
            acc[4+mi][2+nj] = __builtin_amdgcn_mfma_f32_16x16x32_bf16(
                a[mi*2+kk], b1[nj*2+kk], acc[4+mi][2+nj], 0, 0, 0);
      __builtin_amdgcn_s_setprio(0);
      __builtin_amdgcn_s_barrier();

      // ======== phase 4: no reads; stage (u+2)B1; vmcnt at tile end
      if (u < NT-2) stage(gB1, 32768 + buf*16384 + 8192, (u+2)*64);
      __builtin_amdgcn_s_barrier();
      __builtin_amdgcn_s_setprio(1);
#pragma unroll
      for (int mi = 0; mi < 4; ++mi)
#pragma unroll
        for (int nj = 0; nj < 2; ++nj)
#pragma unroll
          for (int kk = 0; kk < 2; ++kk)
            acc[4+mi][nj] = __builtin_amdgcn_mfma_f32_16x16x32_bf16(
                a[mi*2+kk], b0[nj*2+kk], acc[4+mi][nj], 0, 0, 0);
      __builtin_amdgcn_s_setprio(0);
      if (u < NT-2)       { asm volatile("s_waitcnt vmcnt(6)" ::: "memory"); }
      else if (u == NT-2) { asm volatile("s_waitcnt vmcnt(0)" ::: "memory"); }
      __builtin_amdgcn_s_barrier();
    }
  }

  // epilogue: D layout col = fr, row = fk*4 + q
#pragma unroll
  for (int n = 0; n < 4; ++n) {
    const int col = bcol + n * 64 + wc * 16 + fr;
    const float bias = b2[col];
#pragma unroll
    for (int m = 0; m < 8; ++m) {
      const int row0 = brow + m * 32 + wr * 16 + fk * 4;
      float* cp = C + (size_t)row0 * KOUT + col;
#pragma unroll
      for (int q = 0; q < 4; ++q)
        cp[(size_t)q * KOUT] = acc[m][n][q] + bias;
    }
  }
}

// ---------------------------------------------------------------------------
extern "C" void kernel_launch(void* const* d_in, const int* in_sizes, int n_in,
                              void* d_out, int out_size, void* d_ws, size_t ws_size,
                              hipStream_t stream) {
  const float* x  = (const float*)d_in[0];
  const float* G  = (const float*)d_in[1];
  const float* H  = (const float*)d_in[2];
  const float* b1 = (const float*)d_in[3];
  const float* W2 = (const float*)d_in[4];
  const float* b2 = (const float*)d_in[5];
  float* y = (float*)d_out;

  bf16* hbuf = (bf16*)d_ws;                       // 8192*4096*2 = 64 MiB
  bf16* w2t  = hbuf + (size_t)MB * NN;            // 4096*4096*2 = 32 MiB

  hipFuncSetAttribute((const void*)k3_gemm256,
                      hipFuncAttributeMaxDynamicSharedMemorySize, 131072);

  hipLaunchKernelGGL(k1_lowrank, dim3(MB / 16), dim3(256), 0, stream,
                     x, G, H, b1, hbuf);
  hipLaunchKernelGGL(k2_w2t, dim3(64 * 64), dim3(256), 0, stream, W2, w2t);
  hipLaunchKernelGGL(k3_gemm256, dim3((MB/256) * (KOUT/256)), dim3(512), 131072,
                     stream, hbuf, w2t, b2, y);
}

// Round 4
// 329.752 us; speedup vs baseline: 1.3186x; 1.0448x over previous
//
#include <hip/hip_runtime.h>
#include <hip/hip_bf16.h>
#include <cstdint>
#include <cstddef>

typedef __bf16 bf16;
typedef __bf16 bf16x4 __attribute__((ext_vector_type(4)));
typedef __bf16 bf16x8 __attribute__((ext_vector_type(8)));
typedef float  f32x4  __attribute__((ext_vector_type(4)));

#define MB   8192
#define NN   4096
#define RR   16
#define KOUT 4096

// ---------------------------------------------------------------------------
// async global->LDS (16B per lane). LDS dest: wave-uniform base + lane*16.
__device__ __forceinline__ void gload_lds16(const bf16* g, bf16* l) {
  __builtin_amdgcn_global_load_lds(
      (const __attribute__((address_space(1))) void*)g,
      (__attribute__((address_space(3))) void*)l, 16, 0, 0);
}

// ---------------------------------------------------------------------------
// Kernel 1: per block = 16 rows of x.
__global__ __launch_bounds__(256) void k1_lowrank(
    const float* __restrict__ x, const float* __restrict__ G,
    const float* __restrict__ H, const float* __restrict__ b1,
    bf16* __restrict__ hout)
{
  __shared__ float sS[16][16];
  const int t    = threadIdx.x;
  const int lane = t & 63;
  const int wave = t >> 6;
  const int r0   = blockIdx.x * 16;
  const int i0   = wave * 4;

  float acc[4][RR];
#pragma unroll
  for (int j = 0; j < 4; ++j)
#pragma unroll
    for (int r = 0; r < RR; ++r) acc[j][r] = 0.f;

  for (int kt = 0; kt < NN; kt += 256) {
    const int k = kt + lane * 4;
    f32x4 xv[4];
#pragma unroll
    for (int j = 0; j < 4; ++j)
      xv[j] = *(const f32x4*)(x + (size_t)(r0 + i0 + j) * NN + k);
#pragma unroll
    for (int r = 0; r < RR; ++r) {
      const f32x4 hv = *(const f32x4*)(H + (size_t)r * NN + k);
#pragma unroll
      for (int j = 0; j < 4; ++j) {
        acc[j][r] = fmaf(xv[j].x, hv.x, acc[j][r]);
        acc[j][r] = fmaf(xv[j].y, hv.y, acc[j][r]);
        acc[j][r] = fmaf(xv[j].z, hv.z, acc[j][r]);
        acc[j][r] = fmaf(xv[j].w, hv.w, acc[j][r]);
      }
    }
  }

#pragma unroll
  for (int j = 0; j < 4; ++j)
#pragma unroll
    for (int r = 0; r < RR; ++r) {
      float v = acc[j][r];
#pragma unroll
      for (int off = 32; off >= 1; off >>= 1) v += __shfl_xor(v, off, 64);
      acc[j][r] = v;
    }
  if (lane == 0) {
#pragma unroll
    for (int j = 0; j < 4; ++j)
#pragma unroll
      for (int r = 0; r < RR; ++r) sS[i0 + j][r] = acc[j][r];
  }
  __syncthreads();

#pragma unroll
  for (int chunk = 0; chunk < 4; ++chunk) {
    const int c = chunk * 1024 + t * 4;
    const f32x4 b1v = *(const f32x4*)(b1 + c);
#pragma unroll
    for (int ib = 0; ib < 16; ib += 4) {
      f32x4 a0 = {0.f,0.f,0.f,0.f}, a1 = a0, a2 = a0, a3 = a0;
#pragma unroll
      for (int rb = 0; rb < 16; rb += 4) {
        const f32x4 sv0 = *(const f32x4*)&sS[ib + 0][rb];
        const f32x4 sv1 = *(const f32x4*)&sS[ib + 1][rb];
        const f32x4 sv2 = *(const f32x4*)&sS[ib + 2][rb];
        const f32x4 sv3 = *(const f32x4*)&sS[ib + 3][rb];
#pragma unroll
        for (int rr = 0; rr < 4; ++rr) {
          const f32x4 g4 = *(const f32x4*)(G + (size_t)(rb + rr) * NN + c);
          a0 += sv0[rr] * g4;
          a1 += sv1[rr] * g4;
          a2 += sv2[rr] * g4;
          a3 += sv3[rr] * g4;
        }
      }
#define STORE_ROW(jj, av) {                                        \
      const f32x4 hv = (av) + b1v;                                 \
      bf16x4 o;                                                    \
      o[0] = (bf16)fmaxf(hv[0], 0.f); o[1] = (bf16)fmaxf(hv[1], 0.f); \
      o[2] = (bf16)fmaxf(hv[2], 0.f); o[3] = (bf16)fmaxf(hv[3], 0.f); \
      *(bf16x4*)(hout + (size_t)(r0 + ib + (jj)) * NN + c) = o; }
      STORE_ROW(0, a0) STORE_ROW(1, a1) STORE_ROW(2, a2) STORE_ROW(3, a3)
#undef STORE_ROW
    }
  }
}

// ---------------------------------------------------------------------------
// Kernel 2: W2t[o][n] = (bf16)W2[n][o]
__global__ __launch_bounds__(256) void k2_w2t(
    const float* __restrict__ W2, bf16* __restrict__ W2t)
{
  __shared__ float tile[64][65];
  const int t    = threadIdx.x;
  const int kb   = (blockIdx.x >> 6) * 64;
  const int ob   = (blockIdx.x & 63) * 64;
  const int row  = t >> 4;
  const int col4 = (t & 15) * 4;
#pragma unroll
  for (int p = 0; p < 4; ++p) {
    const f32x4 v = *(const f32x4*)(W2 + (size_t)(kb + p*16 + row) * KOUT + ob + col4);
    tile[p*16 + row][col4 + 0] = v[0];
    tile[p*16 + row][col4 + 1] = v[1];
    tile[p*16 + row][col4 + 2] = v[2];
    tile[p*16 + row][col4 + 3] = v[3];
  }
  __syncthreads();
  const int jj0 = t >> 4;
  const int ii4 = (t & 15) * 4;
#pragma unroll
  for (int p = 0; p < 4; ++p) {
    const int jj = p*16 + jj0;
    bf16x4 o;
    o[0] = (bf16)tile[ii4 + 0][jj];
    o[1] = (bf16)tile[ii4 + 1][jj];
    o[2] = (bf16)tile[ii4 + 2][jj];
    o[3] = (bf16)tile[ii4 + 3][jj];
    *(bf16x4*)(W2t + (size_t)(ob + jj) * NN + kb + ii4) = o;
  }
}

// ---------------------------------------------------------------------------
// Kernel 3: 256x256 8-phase bf16 GEMM, register-fragment software pipeline.
// Reads for phase p+1 are issued inside phase p's MFMA region, so ds_read
// latency hides under MFMA. Per tile: P1{stage A1(u+1); Q1=Am0xBn0; read Bn1}
// P2{stage A0(u+2); Q2=Am0xBn1; read Am1} P3{stage B0(u+2); Q3=Am1xBn1}
// P4{stage B1(u+2); vmcnt(6); Q4=Am1xBn0; read next Am0,Bn0}.
// Swizzle: byte ^= (row&7)<<4 (conflict-free, verified R3).
#define NT 64   // K tiles = 4096/64

__global__ __launch_bounds__(512, 1) void k3_gemm256(
    const bf16* __restrict__ A, const bf16* __restrict__ Bt,
    const float* __restrict__ b2, float* __restrict__ C)
{
  extern __shared__ __align__(16) char smem[];
  bf16* lds = (bf16*)smem;
  const char* ldsc = (const char*)smem;

  // bijective XCD swizzle: 512 blocks, 512 % 8 == 0
  const int bid = blockIdx.x;
  const int swz = (bid & 7) * 64 + (bid >> 3);
  const int tm = swz >> 4, tn = swz & 15;       // 32 x 16 tiles
  const int brow = tm * 256, bcol = tn * 256;

  const int t    = threadIdx.x;
  const int lane = t & 63;
  const int wave = t >> 6;
  const int wr   = wave >> 2;   // 0..1  (M)
  const int wc   = wave & 3;    // 0..3  (N)
  const int fr   = lane & 15;
  const int fk   = lane >> 4;

  // staging source coords: linear LDS dest byte d holds logical byte
  // l = d ^ ((row&7)<<4)
  int srow[2], scol[2];
#pragma unroll
  for (int i = 0; i < 2; ++i) {
    const int d   = i * 8192 + t * 16;
    const int row = d >> 7;
    const int l   = d ^ ((row & 7) << 4);
    srow[i] = row;
    scol[i] = (l & 127) >> 1;
  }
  const bf16* gA0 = A  + (size_t)brow * NN;
  const bf16* gA1 = A  + (size_t)(brow + 128) * NN;
  const bf16* gB0 = Bt + (size_t)bcol * NN;
  const bf16* gB1 = Bt + (size_t)(bcol + 128) * NN;

  // A region elem offs: buf*16384 + half*8192 ; B adds 32768
  auto stage = [&](const bf16* g, int regionElem, int kt) {
#pragma unroll
    for (int i = 0; i < 2; ++i)
      gload_lds16(g + (size_t)srow[i] * NN + kt + scol[i],
                  lds + regionElem + i * 4096 + t * 8);
  };

  auto offA = [&](int mi, int kk) -> int {
    const int row = mi * 32 + wr * 16 + fr;
    const int b = row * 128 + kk * 64 + fk * 16;
    return b ^ ((row & 7) << 4);
  };
  auto offB = [&](int nj, int kk) -> int {
    const int row = nj * 64 + wc * 16 + fr;
    const int b = row * 128 + kk * 64 + fk * 16;
    return b ^ ((row & 7) << 4);
  };

  f32x4 acc[8][4];
#pragma unroll
  for (int m = 0; m < 8; ++m)
#pragma unroll
    for (int n = 0; n < 4; ++n) acc[m][n] = (f32x4){0.f,0.f,0.f,0.f};

  bf16x8 a[8], b0[4], b1[4];

  // ---- prologue: tile0 {A0,B0,B1,A1}, tile1 {A0,B0,B1}; then pre-read
  stage(gA0, 0,           0); stage(gB0, 32768,       0);
  stage(gB1, 32768+8192,  0); stage(gA1, 8192,        0);
  stage(gA0, 16384,       64); stage(gB0, 32768+16384, 64);
  stage(gB1, 32768+16384+8192, 64);
  asm volatile("s_waitcnt vmcnt(6)" ::: "memory");
  __builtin_amdgcn_s_barrier();
  asm volatile("" ::: "memory");
#pragma unroll
  for (int mi = 0; mi < 4; ++mi)
#pragma unroll
    for (int kk = 0; kk < 2; ++kk)
      a[mi*2+kk] = *(const bf16x8*)(ldsc + offA(mi, kk));
#pragma unroll
  for (int nj = 0; nj < 2; ++nj)
#pragma unroll
    for (int kk = 0; kk < 2; ++kk)
      b0[nj*2+kk] = *(const bf16x8*)(ldsc + 65536 + offB(nj, kk));

#pragma unroll 1
  for (int u0 = 0; u0 < NT; u0 += 2) {
#pragma unroll
    for (int hi = 0; hi < 2; ++hi) {
      const int u   = u0 + hi;
      const int buf = hi;
      const int obuf = buf ^ 1;
      const char* pa  = ldsc + buf  * 32768;
      const char* pb  = ldsc + 65536 + buf  * 32768;
      const char* pan = ldsc + obuf * 32768;
      const char* pbn = ldsc + 65536 + obuf * 32768;

      // ==== P1: Q1 = Am0 x Bn0 ; read Bn1 for P2 ; stage (u+1)A1
      if (u < NT-1) stage(gA1, obuf*16384 + 8192, (u+1)*64);
      __builtin_amdgcn_s_barrier();
      __builtin_amdgcn_s_setprio(1);
#pragma unroll
      for (int mi = 0; mi < 4; ++mi)
#pragma unroll
        for (int nj = 0; nj < 2; ++nj)
#pragma unroll
          for (int kk = 0; kk < 2; ++kk)
            acc[mi][nj] = __builtin_amdgcn_mfma_f32_16x16x32_bf16(
                a[mi*2+kk], b0[nj*2+kk], acc[mi][nj], 0, 0, 0);
#pragma unroll
      for (int nj = 0; nj < 2; ++nj)
#pragma unroll
        for (int kk = 0; kk < 2; ++kk)
          b1[nj*2+kk] = *(const bf16x8*)(pb + 16384 + offB(nj, kk));
      __builtin_amdgcn_s_setprio(0);
      __builtin_amdgcn_s_barrier();

      // ==== P2: Q2 = Am0 x Bn1 ; read Am1 for P3 ; stage (u+2)A0
      if (u < NT-2) stage(gA0, buf*16384, (u+2)*64);
      __builtin_amdgcn_s_barrier();
      __builtin_amdgcn_s_setprio(1);
#pragma unroll
      for (int mi = 0; mi < 4; ++mi)
#pragma unroll
        for (int nj = 0; nj < 2; ++nj)
#pragma unroll
          for (int kk = 0; kk < 2; ++kk)
            acc[mi][2+nj] = __builtin_amdgcn_mfma_f32_16x16x32_bf16(
                a[mi*2+kk], b1[nj*2+kk], acc[mi][2+nj], 0, 0, 0);
#pragma unroll
      for (int mi = 0; mi < 4; ++mi)
#pragma unroll
        for (int kk = 0; kk < 2; ++kk)
          a[mi*2+kk] = *(const bf16x8*)(pa + 16384 + offA(mi, kk));
      __builtin_amdgcn_s_setprio(0);
      __builtin_amdgcn_s_barrier();

      // ==== P3: Q3 = Am1 x Bn1 ; no reads ; stage (u+2)B0
      if (u < NT-2) stage(gB0, 32768 + buf*16384, (u+2)*64);
      __builtin_amdgcn_s_barrier();
      __builtin_amdgcn_s_setprio(1);
#pragma unroll
      for (int mi = 0; mi < 4; ++mi)
#pragma unroll
        for (int nj = 0; nj < 2; ++nj)
#pragma unroll
          for (int kk = 0; kk < 2; ++kk)
            acc[4+mi][2+nj] = __builtin_amdgcn_mfma_f32_16x16x32_bf16(
                a[mi*2+kk], b1[nj*2+kk], acc[4+mi][2+nj], 0, 0, 0);
      __builtin_amdgcn_s_setprio(0);
      __builtin_amdgcn_s_barrier();

      // ==== P4: Q4 = Am1 x Bn0 ; read next-tile Am0,Bn0 ; stage (u+2)B1
      if (u < NT-2) stage(gB1, 32768 + buf*16384 + 8192, (u+2)*64);
      if (u < NT-2)       { asm volatile("s_waitcnt vmcnt(6)" ::: "memory"); }
      else if (u == NT-2) { asm volatile("s_waitcnt vmcnt(0)" ::: "memory"); }
      __builtin_amdgcn_s_barrier();
      asm volatile("" ::: "memory");
      __builtin_amdgcn_s_setprio(1);
#pragma unroll
      for (int mi = 0; mi < 4; ++mi)
#pragma unroll
        for (int nj = 0; nj < 2; ++nj)
#pragma unroll
          for (int kk = 0; kk < 2; ++kk)
            acc[4+mi][nj] = __builtin_amdgcn_mfma_f32_16x16x32_bf16(
                a[mi*2+kk], b0[nj*2+kk], acc[4+mi][nj], 0, 0, 0);
      if (u < NT-1) {
#pragma unroll
        for (int mi = 0; mi < 4; ++mi)
#pragma unroll
          for (int kk = 0; kk < 2; ++kk)
            a[mi*2+kk] = *(const bf16x8*)(pan + offA(mi, kk));
#pragma unroll
        for (int nj = 0; nj < 2; ++nj)
#pragma unroll
          for (int kk = 0; kk < 2; ++kk)
            b0[nj*2+kk] = *(const bf16x8*)(pbn + offB(nj, kk));
      }
      __builtin_amdgcn_s_setprio(0);
      __builtin_amdgcn_s_barrier();
    }
  }

  // epilogue: D layout col = fr, row = fk*4 + q
#pragma unroll
  for (int n = 0; n < 4; ++n) {
    const int col = bcol + n * 64 + wc * 16 + fr;
    const float bias = b2[col];
#pragma unroll
    for (int m = 0; m < 8; ++m) {
      const int row0 = brow + m * 32 + wr * 16 + fk * 4;
      float* cp = C + (size_t)row0 * KOUT + col;
#pragma unroll
      for (int q = 0; q < 4; ++q)
        cp[(size_t)q * KOUT] = acc[m][n][q] + bias;
    }
  }
}

// ---------------------------------------------------------------------------
extern "C" void kernel_launch(void* const* d_in, const int* in_sizes, int n_in,
                              void* d_out, int out_size, void* d_ws, size_t ws_size,
                              hipStream_t stream) {
  const float* x  = (const float*)d_in[0];
  const float* G  = (const float*)d_in[1];
  const float* H  = (const float*)d_in[2];
  const float* b1 = (const float*)d_in[3];
  const float* W2 = (const float*)d_in[4];
  const float* b2 = (const float*)d_in[5];
  float* y = (float*)d_out;

  bf16* hbuf = (bf16*)d_ws;                       // 8192*4096*2 = 64 MiB
  bf16* w2t  = hbuf + (size_t)MB * NN;            // 4096*4096*2 = 32 MiB

  hipFuncSetAttribute((const void*)k3_gemm256,
                      hipFuncAttributeMaxDynamicSharedMemorySize, 131072);

  hipLaunchKernelGGL(k1_lowrank, dim3(MB / 16), dim3(256), 0, stream,
                     x, G, H, b1, hbuf);
  hipLaunchKernelGGL(k2_w2t, dim3(64 * 64), dim3(256), 0, stream, W2, w2t);
  hipLaunchKernelGGL(k3_gemm256, dim3((MB/256) * (KOUT/256)), dim3(512), 131072,
                     stream, hbuf, w2t, b2, y);
}

// Round 5
// 300.338 us; speedup vs baseline: 1.4478x; 1.0979x over previous
//
#include <hip/hip_runtime.h>
#include <hip/hip_bf16.h>
#include <cstdint>
#include <cstddef>

typedef __bf16 bf16;
typedef __bf16 bf16x4 __attribute__((ext_vector_type(4)));
typedef __bf16 bf16x8 __attribute__((ext_vector_type(8)));
typedef float  f32x4  __attribute__((ext_vector_type(4)));
typedef float  f32x8  __attribute__((ext_vector_type(8)));

#define MB   8192
#define NN   4096
#define RR   16
#define KOUT 4096

#define FENCE() asm volatile("" ::: "memory")
#define BARRIER() do { FENCE(); __builtin_amdgcn_s_barrier(); FENCE(); } while (0)

// ---------------------------------------------------------------------------
// async global->LDS (16B per lane). LDS dest: wave-uniform base + lane*16.
__device__ __forceinline__ void gload_lds16(const bf16* g, bf16* l) {
  __builtin_amdgcn_global_load_lds(
      (const __attribute__((address_space(1))) void*)g,
      (__attribute__((address_space(3))) void*)l, 16, 0, 0);
}

// ---------------------------------------------------------------------------
// Kernel 1a: xH[8192][16] = x @ H^T via MFMA (bf16 inputs, f32 acc).
// 512 blocks x 16 rows; 4 waves K-split 1024 each; LDS reduce.
__global__ __launch_bounds__(256) void k1a_xh(
    const float* __restrict__ x, const float* __restrict__ H,
    float* __restrict__ xH)
{
  __shared__ float red[4][64][4];
  const int t = threadIdx.x, lane = t & 63, w = t >> 6;
  const int r0 = blockIdx.x * 16;
  const int fr = lane & 15, fk = lane >> 4;

  const float* xp = x + (size_t)(r0 + fr) * NN + w * 1024 + fk * 8;
  const float* hp = H + (size_t)fr * NN + w * 1024 + fk * 8;

  f32x4 acc = {0.f, 0.f, 0.f, 0.f};
#pragma unroll 4
  for (int c = 0; c < 32; ++c) {
    const f32x4 xa = *(const f32x4*)(xp + c * 32);
    const f32x4 xb = *(const f32x4*)(xp + c * 32 + 4);
    const f32x4 ha = *(const f32x4*)(hp + c * 32);
    const f32x4 hb = *(const f32x4*)(hp + c * 32 + 4);
    bf16x8 af, bfv;
#pragma unroll
    for (int j = 0; j < 4; ++j) {
      af[j] = (bf16)xa[j]; af[4 + j] = (bf16)xb[j];
      bfv[j] = (bf16)ha[j]; bfv[4 + j] = (bf16)hb[j];
    }
    acc = __builtin_amdgcn_mfma_f32_16x16x32_bf16(af, bfv, acc, 0, 0, 0);
  }
  *(f32x4*)&red[w][lane][0] = acc;
  __syncthreads();
  if (t < 64) {
    f32x4 s = *(const f32x4*)&red[0][t][0];
    s += *(const f32x4*)&red[1][t][0];
    s += *(const f32x4*)&red[2][t][0];
    s += *(const f32x4*)&red[3][t][0];
#pragma unroll
    for (int q = 0; q < 4; ++q)
      xH[(size_t)(r0 + (t >> 4) * 4 + q) * RR + (t & 15)] = s[q];
  }
}

// ---------------------------------------------------------------------------
// Kernel 1b: h = relu(xH @ G + b1) -> bf16.  2048 blocks x 4 rows.
__global__ __launch_bounds__(256) void k1b_h(
    const float* __restrict__ xH, const float* __restrict__ G,
    const float* __restrict__ b1, bf16* __restrict__ hout)
{
  const int t = threadIdx.x;
  const int r0 = blockIdx.x * 4;

  float xh[4][16];
#pragma unroll
  for (int row = 0; row < 4; ++row)
#pragma unroll
    for (int j = 0; j < 16; j += 4)
      *(f32x4*)&xh[row][j] = *(const f32x4*)(xH + (size_t)(r0 + row) * RR + j);

#pragma unroll
  for (int half = 0; half < 2; ++half) {
    const int col = half * 2048 + t * 8;
    const f32x8 bv = *(const f32x8*)(b1 + col);
    f32x8 a0 = bv, a1 = bv, a2 = bv, a3 = bv;
#pragma unroll
    for (int r = 0; r < 16; ++r) {
      const f32x8 g8 = *(const f32x8*)(G + (size_t)r * NN + col);
      a0 += xh[0][r] * g8;
      a1 += xh[1][r] * g8;
      a2 += xh[2][r] * g8;
      a3 += xh[3][r] * g8;
    }
#define STORE_ROW(rr, av) {                                          \
      bf16x8 o;                                                      \
      _Pragma("unroll")                                              \
      for (int j = 0; j < 8; ++j) o[j] = (bf16)fmaxf((av)[j], 0.f);  \
      *(bf16x8*)(hout + (size_t)(r0 + (rr)) * NN + col) = o; }
    STORE_ROW(0, a0) STORE_ROW(1, a1) STORE_ROW(2, a2) STORE_ROW(3, a3)
#undef STORE_ROW
  }
}

// ---------------------------------------------------------------------------
// Kernel 2: W2t[o][n] = (bf16)W2[n][o]
__global__ __launch_bounds__(256) void k2_w2t(
    const float* __restrict__ W2, bf16* __restrict__ W2t)
{
  __shared__ float tile[64][65];
  const int t    = threadIdx.x;
  const int kb   = (blockIdx.x >> 6) * 64;
  const int ob   = (blockIdx.x & 63) * 64;
  const int row  = t >> 4;
  const int col4 = (t & 15) * 4;
#pragma unroll
  for (int p = 0; p < 4; ++p) {
    const f32x4 v = *(const f32x4*)(W2 + (size_t)(kb + p*16 + row) * KOUT + ob + col4);
    tile[p*16 + row][col4 + 0] = v[0];
    tile[p*16 + row][col4 + 1] = v[1];
    tile[p*16 + row][col4 + 2] = v[2];
    tile[p*16 + row][col4 + 3] = v[3];
  }
  __syncthreads();
  const int jj0 = t >> 4;
  const int ii4 = (t & 15) * 4;
#pragma unroll
  for (int p = 0; p < 4; ++p) {
    const int jj = p*16 + jj0;
    bf16x4 o;
    o[0] = (bf16)tile[ii4 + 0][jj];
    o[1] = (bf16)tile[ii4 + 1][jj];
    o[2] = (bf16)tile[ii4 + 2][jj];
    o[3] = (bf16)tile[ii4 + 3][jj];
    *(bf16x4*)(W2t + (size_t)(ob + jj) * NN + kb + ii4) = o;
  }
}

// ---------------------------------------------------------------------------
// Kernel 3: 256x256 bf16 GEMM, 3 barriers/K-tile.
// Barrier ledger (regions A0/A1/B0/B1 x 2 buf-parities):
//   A0(v): staged P2(v-2) [after P2-entry], read P4(v-1) pre-read, ok.
//   A1(v): staged P1(v-1), read P2(v) cluster.
//   B0(v): staged P3(v-2), read P4(v-1) pre-read.
//   B1(v): staged P4(v-2), read P1(v) cluster.
// Guards: vmcnt(6)+P4-entry barrier = all of tile v+1 landed before P4
// pre-reads; P2-entry separates P1-cluster reads from P4's B1 stage;
// P4-exit separates P4 pre-reads from next tile's stages.  Every stage
// issue is >=1 barrier after its region's last reader under any drift.
#define NT 64   // K tiles = 4096/64

__global__ __launch_bounds__(512, 1) void k3_gemm256(
    const bf16* __restrict__ A, const bf16* __restrict__ Bt,
    const float* __restrict__ b2, float* __restrict__ C)
{
  extern __shared__ __align__(16) char smem[];
  bf16* lds = (bf16*)smem;
  const char* ldsc = (const char*)smem;

  // bijective XCD swizzle: 512 blocks, 512 % 8 == 0
  const int bid = blockIdx.x;
  const int swz = (bid & 7) * 64 + (bid >> 3);
  const int tm = swz >> 4, tn = swz & 15;       // 32 x 16 tiles
  const int brow = tm * 256, bcol = tn * 256;

  const int t    = threadIdx.x;
  const int lane = t & 63;
  const int wave = t >> 6;
  const int wr   = wave >> 2;   // 0..1  (M)
  const int wc   = wave & 3;    // 0..3  (N)
  const int fr   = lane & 15;
  const int fk   = lane >> 4;

  // staging source coords: linear LDS dest byte d holds logical byte
  // l = d ^ ((row&7)<<4)
  int srow[2], scol[2];
#pragma unroll
  for (int i = 0; i < 2; ++i) {
    const int d   = i * 8192 + t * 16;
    const int row = d >> 7;
    const int l   = d ^ ((row & 7) << 4);
    srow[i] = row;
    scol[i] = (l & 127) >> 1;
  }
  const bf16* gA0 = A  + (size_t)brow * NN;
  const bf16* gA1 = A  + (size_t)(brow + 128) * NN;
  const bf16* gB0 = Bt + (size_t)bcol * NN;
  const bf16* gB1 = Bt + (size_t)(bcol + 128) * NN;

  // A region elem offs: buf*16384 + half*8192 ; B adds 32768
  auto stage = [&](const bf16* g, int regionElem, int kt) {
#pragma unroll
    for (int i = 0; i < 2; ++i)
      gload_lds16(g + (size_t)srow[i] * NN + kt + scol[i],
                  lds + regionElem + i * 4096 + t * 8);
  };

  auto offA = [&](int mi, int kk) -> int {
    const int row = mi * 32 + wr * 16 + fr;
    const int b = row * 128 + kk * 64 + fk * 16;
    return b ^ ((row & 7) << 4);
  };
  auto offB = [&](int nj, int kk) -> int {
    const int row = nj * 64 + wc * 16 + fr;
    const int b = row * 128 + kk * 64 + fk * 16;
    return b ^ ((row & 7) << 4);
  };

  f32x4 acc[8][4];
#pragma unroll
  for (int m = 0; m < 8; ++m)
#pragma unroll
    for (int n = 0; n < 4; ++n) acc[m][n] = (f32x4){0.f,0.f,0.f,0.f};

  bf16x8 a[8], b0[4], b1[4];

  // ---- prologue: tile0 {A0,B0,B1,A1}, tile1 {A0,B0,B1}; then pre-read
  stage(gA0, 0,           0); stage(gB0, 32768,       0);
  stage(gB1, 32768+8192,  0); stage(gA1, 8192,        0);
  stage(gA0, 16384,       64); stage(gB0, 32768+16384, 64);
  stage(gB1, 32768+16384+8192, 64);
  asm volatile("s_waitcnt vmcnt(6)" ::: "memory");
  BARRIER();
#pragma unroll
  for (int mi = 0; mi < 4; ++mi)
#pragma unroll
    for (int kk = 0; kk < 2; ++kk)
      a[mi*2+kk] = *(const bf16x8*)(ldsc + offA(mi, kk));
#pragma unroll
  for (int nj = 0; nj < 2; ++nj)
#pragma unroll
    for (int kk = 0; kk < 2; ++kk)
      b0[nj*2+kk] = *(const bf16x8*)(ldsc + 65536 + offB(nj, kk));

#pragma unroll 1
  for (int u0 = 0; u0 < NT; u0 += 2) {
#pragma unroll
    for (int hi = 0; hi < 2; ++hi) {
      const int u   = u0 + hi;
      const int buf = hi;
      const int obuf = buf ^ 1;
      const char* pa  = ldsc + buf  * 32768;
      const char* pb  = ldsc + 65536 + buf  * 32768;
      const char* pan = ldsc + obuf * 32768;
      const char* pbn = ldsc + 65536 + obuf * 32768;

      // ==== P1 (no barrier): stage (u+1)A1 ; Q1 = Am0 x Bn0 ; read Bn1
      if (u < NT-1) stage(gA1, obuf*16384 + 8192, (u+1)*64);
      __builtin_amdgcn_s_setprio(1);
#pragma unroll
      for (int mi = 0; mi < 4; ++mi)
#pragma unroll
        for (int nj = 0; nj < 2; ++nj)
#pragma unroll
          for (int kk = 0; kk < 2; ++kk)
            acc[mi][nj] = __builtin_amdgcn_mfma_f32_16x16x32_bf16(
                a[mi*2+kk], b0[nj*2+kk], acc[mi][nj], 0, 0, 0);
#pragma unroll
      for (int nj = 0; nj < 2; ++nj)
#pragma unroll
        for (int kk = 0; kk < 2; ++kk)
          b1[nj*2+kk] = *(const bf16x8*)(pb + 16384 + offB(nj, kk));
      __builtin_amdgcn_s_setprio(0);

      // ==== P2: BARRIER ; stage (u+2)A0 ; Q2 = Am0 x Bn1 ; read Am1
      BARRIER();
      if (u < NT-2) stage(gA0, buf*16384, (u+2)*64);
      __builtin_amdgcn_s_setprio(1);
#pragma unroll
      for (int mi = 0; mi < 4; ++mi)
#pragma unroll
        for (int nj = 0; nj < 2; ++nj)
#pragma unroll
          for (int kk = 0; kk < 2; ++kk)
            acc[mi][2+nj] = __builtin_amdgcn_mfma_f32_16x16x32_bf16(
                a[mi*2+kk], b1[nj*2+kk], acc[mi][2+nj], 0, 0, 0);
#pragma unroll
      for (int mi = 0; mi < 4; ++mi)
#pragma unroll
        for (int kk = 0; kk < 2; ++kk)
          a[mi*2+kk] = *(const bf16x8*)(pa + 16384 + offA(mi, kk));
      __builtin_amdgcn_s_setprio(0);

      // ==== P3 (no barrier): stage (u+2)B0 ; Q3 = Am1 x Bn1
      if (u < NT-2) stage(gB0, 32768 + buf*16384, (u+2)*64);
      __builtin_amdgcn_s_setprio(1);
#pragma unroll
      for (int mi = 0; mi < 4; ++mi)
#pragma unroll
        for (int nj = 0; nj < 2; ++nj)
#pragma unroll
          for (int kk = 0; kk < 2; ++kk)
            acc[4+mi][2+nj] = __builtin_amdgcn_mfma_f32_16x16x32_bf16(
                a[mi*2+kk], b1[nj*2+kk], acc[4+mi][2+nj], 0, 0, 0);
      __builtin_amdgcn_s_setprio(0);

      // ==== P4: stage (u+2)B1 ; vmcnt ; BARRIER ; Q4 + next-tile pre-reads ; BARRIER
      if (u < NT-2) stage(gB1, 32768 + buf*16384 + 8192, (u+2)*64);
      if (u < NT-2)       { asm volatile("s_waitcnt vmcnt(6)" ::: "memory"); }
      else if (u == NT-2) { asm volatile("s_waitcnt vmcnt(0)" ::: "memory"); }
      BARRIER();
      __builtin_amdgcn_s_setprio(1);
#pragma unroll
      for (int mi = 0; mi < 4; ++mi)
#pragma unroll
        for (int nj = 0; nj < 2; ++nj)
#pragma unroll
          for (int kk = 0; kk < 2; ++kk)
            acc[4+mi][nj] = __builtin_amdgcn_mfma_f32_16x16x32_bf16(
                a[mi*2+kk], b0[nj*2+kk], acc[4+mi][nj], 0, 0, 0);
      if (u < NT-1) {
#pragma unroll
        for (int mi = 0; mi < 4; ++mi)
#pragma unroll
          for (int kk = 0; kk < 2; ++kk)
            a[mi*2+kk] = *(const bf16x8*)(pan + offA(mi, kk));
#pragma unroll
        for (int nj = 0; nj < 2; ++nj)
#pragma unroll
          for (int kk = 0; kk < 2; ++kk)
            b0[nj*2+kk] = *(const bf16x8*)(pbn + offB(nj, kk));
      }
      __builtin_amdgcn_s_setprio(0);
      BARRIER();
    }
  }

  // epilogue: D layout col = fr, row = fk*4 + q
#pragma unroll
  for (int n = 0; n < 4; ++n) {
    const int col = bcol + n * 64 + wc * 16 + fr;
    const float bias = b2[col];
#pragma unroll
    for (int m = 0; m < 8; ++m) {
      const int row0 = brow + m * 32 + wr * 16 + fk * 4;
      float* cp = C + (size_t)row0 * KOUT + col;
#pragma unroll
      for (int q = 0; q < 4; ++q)
        cp[(size_t)q * KOUT] = acc[m][n][q] + bias;
    }
  }
}

// ---------------------------------------------------------------------------
extern "C" void kernel_launch(void* const* d_in, const int* in_sizes, int n_in,
                              void* d_out, int out_size, void* d_ws, size_t ws_size,
                              hipStream_t stream) {
  const float* x  = (const float*)d_in[0];
  const float* G  = (const float*)d_in[1];
  const float* H  = (const float*)d_in[2];
  const float* b1 = (const float*)d_in[3];
  const float* W2 = (const float*)d_in[4];
  const float* b2 = (const float*)d_in[5];
  float* y = (float*)d_out;

  bf16*  hbuf = (bf16*)d_ws;                         // 8192*4096*2 = 64 MiB
  bf16*  w2t  = hbuf + (size_t)MB * NN;              // 4096*4096*2 = 32 MiB
  float* xhb  = (float*)(w2t + (size_t)NN * KOUT);   // 8192*16*4 = 512 KiB

  hipFuncSetAttribute((const void*)k3_gemm256,
                      hipFuncAttributeMaxDynamicSharedMemorySize, 131072);

  hipLaunchKernelGGL(k1a_xh, dim3(MB / 16), dim3(256), 0, stream, x, H, xhb);
  hipLaunchKernelGGL(k1b_h,  dim3(MB / 4),  dim3(256), 0, stream, xhb, G, b1, hbuf);
  hipLaunchKernelGGL(k2_w2t, dim3(64 * 64), dim3(256), 0, stream, W2, w2t);
  hipLaunchKernelGGL(k3_gemm256, dim3((MB/256) * (KOUT/256)), dim3(512), 131072,
                     stream, hbuf, w2t, b2, y);
}

// Round 6
// 294.550 us; speedup vs baseline: 1.4762x; 1.0196x over previous
//
#include <hip/hip_runtime.h>
#include <hip/hip_bf16.h>
#include <cstdint>
#include <cstddef>

typedef __bf16 bf16;
typedef __bf16 bf16x4 __attribute__((ext_vector_type(4)));
typedef __bf16 bf16x8 __attribute__((ext_vector_type(8)));
typedef float  f32x4  __attribute__((ext_vector_type(4)));
typedef float  f32x8  __attribute__((ext_vector_type(8)));

#define MB   8192
#define NN   4096
#define RR   16
#define KOUT 4096

#define FENCE() asm volatile("" ::: "memory")
#define BARRIER() do { FENCE(); __builtin_amdgcn_s_barrier(); FENCE(); } while (0)

// ---------------------------------------------------------------------------
// async global->LDS (16B per lane). LDS dest: wave-uniform base + lane*16.
__device__ __forceinline__ void gload_lds16(const bf16* g, bf16* l) {
  __builtin_amdgcn_global_load_lds(
      (const __attribute__((address_space(1))) void*)g,
      (__attribute__((address_space(3))) void*)l, 16, 0, 0);
}

// ---------------------------------------------------------------------------
// Fused dispatch 1: blocks [0,512) = xH = x@H^T (MFMA);  blocks [512,4608) =
// W2t[o][n] = (bf16)W2[n][o].  Independent roles; packs both HBM streams.
__global__ __launch_bounds__(256) void f1_xh_w2t(
    const float* __restrict__ x, const float* __restrict__ H,
    float* __restrict__ xH,
    const float* __restrict__ W2, bf16* __restrict__ W2t)
{
  __shared__ float red[4][64][4];      // k1a role (4 KB)
  __shared__ float tile[64][65];       // k2 role (16.6 KB)
  const int t = threadIdx.x;

  if (blockIdx.x < 512) {
    // ---- role A: xH[8192][16] = x @ H^T via MFMA (bf16 in, f32 acc)
    const int lane = t & 63, w = t >> 6;
    const int r0 = blockIdx.x * 16;
    const int fr = lane & 15, fk = lane >> 4;

    const float* xp = x + (size_t)(r0 + fr) * NN + w * 1024 + fk * 8;
    const float* hp = H + (size_t)fr * NN + w * 1024 + fk * 8;

    f32x4 acc = {0.f, 0.f, 0.f, 0.f};
#pragma unroll 4
    for (int c = 0; c < 32; ++c) {
      const f32x4 xa = *(const f32x4*)(xp + c * 32);
      const f32x4 xb = *(const f32x4*)(xp + c * 32 + 4);
      const f32x4 ha = *(const f32x4*)(hp + c * 32);
      const f32x4 hb = *(const f32x4*)(hp + c * 32 + 4);
      bf16x8 af, bfv;
#pragma unroll
      for (int j = 0; j < 4; ++j) {
        af[j] = (bf16)xa[j]; af[4 + j] = (bf16)xb[j];
        bfv[j] = (bf16)ha[j]; bfv[4 + j] = (bf16)hb[j];
      }
      acc = __builtin_amdgcn_mfma_f32_16x16x32_bf16(af, bfv, acc, 0, 0, 0);
    }
    *(f32x4*)&red[w][lane][0] = acc;
    __syncthreads();
    if (t < 64) {
      f32x4 s = *(const f32x4*)&red[0][t][0];
      s += *(const f32x4*)&red[1][t][0];
      s += *(const f32x4*)&red[2][t][0];
      s += *(const f32x4*)&red[3][t][0];
#pragma unroll
      for (int q = 0; q < 4; ++q)
        xH[(size_t)(r0 + (t >> 4) * 4 + q) * RR + (t & 15)] = s[q];
    }
  } else {
    // ---- role B: W2 transpose-cast (64x64 LDS tile)
    const int bid  = blockIdx.x - 512;
    const int kb   = (bid >> 6) * 64;
    const int ob   = (bid & 63) * 64;
    const int row  = t >> 4;
    const int col4 = (t & 15) * 4;
#pragma unroll
    for (int p = 0; p < 4; ++p) {
      const f32x4 v = *(const f32x4*)(W2 + (size_t)(kb + p*16 + row) * KOUT + ob + col4);
      tile[p*16 + row][col4 + 0] = v[0];
      tile[p*16 + row][col4 + 1] = v[1];
      tile[p*16 + row][col4 + 2] = v[2];
      tile[p*16 + row][col4 + 3] = v[3];
    }
    __syncthreads();
    const int jj0 = t >> 4;
    const int ii4 = (t & 15) * 4;
#pragma unroll
    for (int p = 0; p < 4; ++p) {
      const int jj = p*16 + jj0;
      bf16x4 o;
      o[0] = (bf16)tile[ii4 + 0][jj];
      o[1] = (bf16)tile[ii4 + 1][jj];
      o[2] = (bf16)tile[ii4 + 2][jj];
      o[3] = (bf16)tile[ii4 + 3][jj];
      *(bf16x4*)(W2t + (size_t)(ob + jj) * NN + kb + ii4) = o;
    }
  }
}

// ---------------------------------------------------------------------------
// Kernel 1b: h = relu(xH @ G + b1) -> bf16.  2048 blocks x 4 rows.
__global__ __launch_bounds__(256) void k1b_h(
    const float* __restrict__ xH, const float* __restrict__ G,
    const float* __restrict__ b1, bf16* __restrict__ hout)
{
  const int t = threadIdx.x;
  const int r0 = blockIdx.x * 4;

  float xh[4][16];
#pragma unroll
  for (int row = 0; row < 4; ++row)
#pragma unroll
    for (int j = 0; j < 16; j += 4)
      *(f32x4*)&xh[row][j] = *(const f32x4*)(xH + (size_t)(r0 + row) * RR + j);

#pragma unroll
  for (int half = 0; half < 2; ++half) {
    const int col = half * 2048 + t * 8;
    const f32x8 bv = *(const f32x8*)(b1 + col);
    f32x8 a0 = bv, a1 = bv, a2 = bv, a3 = bv;
#pragma unroll
    for (int r = 0; r < 16; ++r) {
      const f32x8 g8 = *(const f32x8*)(G + (size_t)r * NN + col);
      a0 += xh[0][r] * g8;
      a1 += xh[1][r] * g8;
      a2 += xh[2][r] * g8;
      a3 += xh[3][r] * g8;
    }
#define STORE_ROW(rr, av) {                                          \
      bf16x8 o;                                                      \
      _Pragma("unroll")                                              \
      for (int j = 0; j < 8; ++j) o[j] = (bf16)fmaxf((av)[j], 0.f);  \
      *(bf16x8*)(hout + (size_t)(r0 + (rr)) * NN + col) = o; }
    STORE_ROW(0, a0) STORE_ROW(1, a1) STORE_ROW(2, a2) STORE_ROW(3, a3)
#undef STORE_ROW
  }
}

// ---------------------------------------------------------------------------
// Kernel 3: 256x256 bf16 GEMM, 3 barriers/K-tile (verified R5: 57% MfmaUtil,
// 0 bank conflicts).  Unchanged this round.
#define NT 64   // K tiles = 4096/64

__global__ __launch_bounds__(512, 1) void k3_gemm256(
    const bf16* __restrict__ A, const bf16* __restrict__ Bt,
    const float* __restrict__ b2, float* __restrict__ C)
{
  extern __shared__ __align__(16) char smem[];
  bf16* lds = (bf16*)smem;
  const char* ldsc = (const char*)smem;

  // bijective XCD swizzle: 512 blocks, 512 % 8 == 0
  const int bid = blockIdx.x;
  const int swz = (bid & 7) * 64 + (bid >> 3);
  const int tm = swz >> 4, tn = swz & 15;       // 32 x 16 tiles
  const int brow = tm * 256, bcol = tn * 256;

  const int t    = threadIdx.x;
  const int lane = t & 63;
  const int wave = t >> 6;
  const int wr   = wave >> 2;   // 0..1  (M)
  const int wc   = wave & 3;    // 0..3  (N)
  const int fr   = lane & 15;
  const int fk   = lane >> 4;

  // staging source coords: linear LDS dest byte d holds logical byte
  // l = d ^ ((row&7)<<4)
  int srow[2], scol[2];
#pragma unroll
  for (int i = 0; i < 2; ++i) {
    const int d   = i * 8192 + t * 16;
    const int row = d >> 7;
    const int l   = d ^ ((row & 7) << 4);
    srow[i] = row;
    scol[i] = (l & 127) >> 1;
  }
  const bf16* gA0 = A  + (size_t)brow * NN;
  const bf16* gA1 = A  + (size_t)(brow + 128) * NN;
  const bf16* gB0 = Bt + (size_t)bcol * NN;
  const bf16* gB1 = Bt + (size_t)(bcol + 128) * NN;

  // A region elem offs: buf*16384 + half*8192 ; B adds 32768
  auto stage = [&](const bf16* g, int regionElem, int kt) {
#pragma unroll
    for (int i = 0; i < 2; ++i)
      gload_lds16(g + (size_t)srow[i] * NN + kt + scol[i],
                  lds + regionElem + i * 4096 + t * 8);
  };

  auto offA = [&](int mi, int kk) -> int {
    const int row = mi * 32 + wr * 16 + fr;
    const int b = row * 128 + kk * 64 + fk * 16;
    return b ^ ((row & 7) << 4);
  };
  auto offB = [&](int nj, int kk) -> int {
    const int row = nj * 64 + wc * 16 + fr;
    const int b = row * 128 + kk * 64 + fk * 16;
    return b ^ ((row & 7) << 4);
  };

  f32x4 acc[8][4];
#pragma unroll
  for (int m = 0; m < 8; ++m)
#pragma unroll
    for (int n = 0; n < 4; ++n) acc[m][n] = (f32x4){0.f,0.f,0.f,0.f};

  bf16x8 a[8], b0[4], b1[4];

  // ---- prologue: tile0 {A0,B0,B1,A1}, tile1 {A0,B0,B1}; then pre-read
  stage(gA0, 0,           0); stage(gB0, 32768,       0);
  stage(gB1, 32768+8192,  0); stage(gA1, 8192,        0);
  stage(gA0, 16384,       64); stage(gB0, 32768+16384, 64);
  stage(gB1, 32768+16384+8192, 64);
  asm volatile("s_waitcnt vmcnt(6)" ::: "memory");
  BARRIER();
#pragma unroll
  for (int mi = 0; mi < 4; ++mi)
#pragma unroll
    for (int kk = 0; kk < 2; ++kk)
      a[mi*2+kk] = *(const bf16x8*)(ldsc + offA(mi, kk));
#pragma unroll
  for (int nj = 0; nj < 2; ++nj)
#pragma unroll
    for (int kk = 0; kk < 2; ++kk)
      b0[nj*2+kk] = *(const bf16x8*)(ldsc + 65536 + offB(nj, kk));

#pragma unroll 1
  for (int u0 = 0; u0 < NT; u0 += 2) {
#pragma unroll
    for (int hi = 0; hi < 2; ++hi) {
      const int u   = u0 + hi;
      const int buf = hi;
      const int obuf = buf ^ 1;
      const char* pa  = ldsc + buf  * 32768;
      const char* pb  = ldsc + 65536 + buf  * 32768;
      const char* pan = ldsc + obuf * 32768;
      const char* pbn = ldsc + 65536 + obuf * 32768;

      // ==== P1 (no barrier): stage (u+1)A1 ; Q1 = Am0 x Bn0 ; read Bn1
      if (u < NT-1) stage(gA1, obuf*16384 + 8192, (u+1)*64);
      __builtin_amdgcn_s_setprio(1);
#pragma unroll
      for (int mi = 0; mi < 4; ++mi)
#pragma unroll
        for (int nj = 0; nj < 2; ++nj)
#pragma unroll
          for (int kk = 0; kk < 2; ++kk)
            acc[mi][nj] = __builtin_amdgcn_mfma_f32_16x16x32_bf16(
                a[mi*2+kk], b0[nj*2+kk], acc[mi][nj], 0, 0, 0);
#pragma unroll
      for (int nj = 0; nj < 2; ++nj)
#pragma unroll
        for (int kk = 0; kk < 2; ++kk)
          b1[nj*2+kk] = *(const bf16x8*)(pb + 16384 + offB(nj, kk));
      __builtin_amdgcn_s_setprio(0);

      // ==== P2: BARRIER ; stage (u+2)A0 ; Q2 = Am0 x Bn1 ; read Am1
      BARRIER();
      if (u < NT-2) stage(gA0, buf*16384, (u+2)*64);
      __builtin_amdgcn_s_setprio(1);
#pragma unroll
      for (int mi = 0; mi < 4; ++mi)
#pragma unroll
        for (int nj = 0; nj < 2; ++nj)
#pragma unroll
          for (int kk = 0; kk < 2; ++kk)
            acc[mi][2+nj] = __builtin_amdgcn_mfma_f32_16x16x32_bf16(
                a[mi*2+kk], b1[nj*2+kk], acc[mi][2+nj], 0, 0, 0);
#pragma unroll
      for (int mi = 0; mi < 4; ++mi)
#pragma unroll
        for (int kk = 0; kk < 2; ++kk)
          a[mi*2+kk] = *(const bf16x8*)(pa + 16384 + offA(mi, kk));
      __builtin_amdgcn_s_setprio(0);

      // ==== P3 (no barrier): stage (u+2)B0 ; Q3 = Am1 x Bn1
      if (u < NT-2) stage(gB0, 32768 + buf*16384, (u+2)*64);
      __builtin_amdgcn_s_setprio(1);
#pragma unroll
      for (int mi = 0; mi < 4; ++mi)
#pragma unroll
        for (int nj = 0; nj < 2; ++nj)
#pragma unroll
          for (int kk = 0; kk < 2; ++kk)
            acc[4+mi][2+nj] = __builtin_amdgcn_mfma_f32_16x16x32_bf16(
                a[mi*2+kk], b1[nj*2+kk], acc[4+mi][2+nj], 0, 0, 0);
      __builtin_amdgcn_s_setprio(0);

      // ==== P4: stage (u+2)B1 ; vmcnt ; BARRIER ; Q4 + next-tile pre-reads ; BARRIER
      if (u < NT-2) stage(gB1, 32768 + buf*16384 + 8192, (u+2)*64);
      if (u < NT-2)       { asm volatile("s_waitcnt vmcnt(6)" ::: "memory"); }
      else if (u == NT-2) { asm volatile("s_waitcnt vmcnt(0)" ::: "memory"); }
      BARRIER();
      __builtin_amdgcn_s_setprio(1);
#pragma unroll
      for (int mi = 0; mi < 4; ++mi)
#pragma unroll
        for (int nj = 0; nj < 2; ++nj)
#pragma unroll
          for (int kk = 0; kk < 2; ++kk)
            acc[4+mi][nj] = __builtin_amdgcn_mfma_f32_16x16x32_bf16(
                a[mi*2+kk], b0[nj*2+kk], acc[4+mi][nj], 0, 0, 0);
      if (u < NT-1) {
#pragma unroll
        for (int mi = 0; mi < 4; ++mi)
#pragma unroll
          for (int kk = 0; kk < 2; ++kk)
            a[mi*2+kk] = *(const bf16x8*)(pan + offA(mi, kk));
#pragma unroll
        for (int nj = 0; nj < 2; ++nj)
#pragma unroll
          for (int kk = 0; kk < 2; ++kk)
            b0[nj*2+kk] = *(const bf16x8*)(pbn + offB(nj, kk));
      }
      __builtin_amdgcn_s_setprio(0);
      BARRIER();
    }
  }

  // epilogue: D layout col = fr, row = fk*4 + q
#pragma unroll
  for (int n = 0; n < 4; ++n) {
    const int col = bcol + n * 64 + wc * 16 + fr;
    const float bias = b2[col];
#pragma unroll
    for (int m = 0; m < 8; ++m) {
      const int row0 = brow + m * 32 + wr * 16 + fk * 4;
      float* cp = C + (size_t)row0 * KOUT + col;
#pragma unroll
      for (int q = 0; q < 4; ++q)
        cp[(size_t)q * KOUT] = acc[m][n][q] + bias;
    }
  }
}

// ---------------------------------------------------------------------------
extern "C" void kernel_launch(void* const* d_in, const int* in_sizes, int n_in,
                              void* d_out, int out_size, void* d_ws, size_t ws_size,
                              hipStream_t stream) {
  const float* x  = (const float*)d_in[0];
  const float* G  = (const float*)d_in[1];
  const float* H  = (const float*)d_in[2];
  const float* b1 = (const float*)d_in[3];
  const float* W2 = (const float*)d_in[4];
  const float* b2 = (const float*)d_in[5];
  float* y = (float*)d_out;

  bf16*  hbuf = (bf16*)d_ws;                         // 8192*4096*2 = 64 MiB
  bf16*  w2t  = hbuf + (size_t)MB * NN;              // 4096*4096*2 = 32 MiB
  float* xhb  = (float*)(w2t + (size_t)NN * KOUT);   // 8192*16*4 = 512 KiB

  hipFuncSetAttribute((const void*)k3_gemm256,
                      hipFuncAttributeMaxDynamicSharedMemorySize, 131072);

  hipLaunchKernelGGL(f1_xh_w2t, dim3(512 + 64 * 64), dim3(256), 0, stream,
                     x, H, xhb, W2, w2t);
  hipLaunchKernelGGL(k1b_h, dim3(MB / 4), dim3(256), 0, stream, xhb, G, b1, hbuf);
  hipLaunchKernelGGL(k3_gemm256, dim3((MB/256) * (KOUT/256)), dim3(512), 131072,
                     stream, hbuf, w2t, b2, y);
}